// Round 1
// baseline (636.985 us; speedup 1.0000x reference)
//
#include <hip/hip_runtime.h>
#include <math.h>

#define NB 32
#define NL 2048
#define NH 8
#define NE 64
#define NM 64
#define LSPLIT 4
#define LCHUNK (NL / LSPLIT)   // 512

// ---------------- table build ----------------
// cosTt/sinTt: gathered-mode DFT twiddles, layout [l][m] (m contiguous)
// ccT/csT:     irfft slot tables, layout [m][l] (l contiguous)
__global__ void build_tables_k(const int* __restrict__ idx,
                               float* __restrict__ cosTt, float* __restrict__ sinTt,
                               float* __restrict__ ccT, float* __restrict__ csT) {
  int gid = blockIdx.x * blockDim.x + threadIdx.x;
  if (gid >= NL * NM) return;
  const float twopi_over_L = 6.283185307179586f / (float)NL;
  // gathered tables: [l][m]
  int l = gid >> 6, m = gid & 63;
  int f = idx[m];
  int ph = (f * l) & (NL - 1);
  float s, c;
  sincosf((float)ph * twopi_over_L, &s, &c);
  cosTt[gid] = c;
  sinTt[gid] = s;
  // slot tables: [m][l]
  int m2 = gid >> 11, l2 = gid & (NL - 1);
  int ph2 = (m2 * l2) & (NL - 1);
  float s2, c2;
  sincosf((float)ph2 * twopi_over_L, &s2, &c2);
  const float inv = 1.0f / (float)NL;
  ccT[gid] = (m2 == 0 ? inv : 2.0f * inv) * c2;
  csT[gid] = (m2 == 0 ? 0.0f : -2.0f * inv * s2);
}

// ---------------- W transpose: w[h][i][o][m] -> Wt[h][m][i][o] ----------------
__global__ void transpose_w_k(const float* __restrict__ wr, const float* __restrict__ wi,
                              float* __restrict__ Wtr, float* __restrict__ Wti) {
  __shared__ float tile[64][65];
  int h = blockIdx.x >> 6, i = blockIdx.x & 63;
  int t = threadIdx.x;
  for (int p = 0; p < 2; ++p) {
    const float* src = (p ? wi : wr) + ((size_t)(h * NE + i)) * NE * NM;  // [o][m]
    float* dst = (p ? Wti : Wtr) + (size_t)h * NM * NE * NE + (size_t)i * NE;
    for (int rep = 0; rep < 16; ++rep) {
      int id = rep * 256 + t;
      tile[id >> 6][id & 63] = src[id];   // coalesced read along m
    }
    __syncthreads();
    for (int rep = 0; rep < 16; ++rep) {
      int id = rep * 256 + t;
      int m = id >> 6, o = id & 63;
      dst[(size_t)m * NE * NE + o] = tile[o][m];  // coalesced write along o
    }
    __syncthreads();
  }
}

// ---------------- stage A: DFT at gathered modes ----------------
// X[s][b][h][m][i] = sum over l in split s of q[b][l][h][i] * (cos, -sin)
__global__ __launch_bounds__(256) void dft_k(const float* __restrict__ q,
                                             const float* __restrict__ cosTt,
                                             const float* __restrict__ sinTt,
                                             float* __restrict__ Xr, float* __restrict__ Xi) {
  int bid = blockIdx.x;               // ((b*NH + h)*LSPLIT + s)
  int s = bid & (LSPLIT - 1);
  int bh = bid >> 2;
  int h = bh & (NH - 1);
  int b = bh >> 3;
  int t = threadIdx.x;
  int ib = t & 15, mb = t >> 4;       // 16 i-blocks x 16 m-blocks
  int i0 = ib * 4, m0 = mb * 4;
  float accr[4][4] = {{0.f}};
  float acci[4][4] = {{0.f}};
  const float4* cos4 = (const float4*)cosTt;
  const float4* sin4 = (const float4*)sinTt;
  const float* qbase = q + ((size_t)b * NL * NH + h) * NE;
  int l0 = s * LCHUNK;
#pragma unroll 4
  for (int l = l0; l < l0 + LCHUNK; ++l) {
    float4 qv = *(const float4*)(qbase + (size_t)l * NH * NE + i0);
    float4 cv = cos4[l * (NM / 4) + mb];
    float4 sv = sin4[l * (NM / 4) + mb];
    float qa[4] = {qv.x, qv.y, qv.z, qv.w};
    float ca[4] = {cv.x, cv.y, cv.z, cv.w};
    float sa[4] = {sv.x, sv.y, sv.z, sv.w};
#pragma unroll
    for (int j = 0; j < 4; ++j)
#pragma unroll
      for (int k = 0; k < 4; ++k) {
        accr[j][k] += qa[k] * ca[j];
        acci[j][k] -= qa[k] * sa[j];
      }
  }
  size_t xb = (((size_t)s * NB * NH + (size_t)b * NH + h) * NM) * NE;
#pragma unroll
  for (int j = 0; j < 4; ++j) {
    size_t off = xb + (size_t)(m0 + j) * NE + i0;
    *(float4*)(Xr + off) = make_float4(accr[j][0], accr[j][1], accr[j][2], accr[j][3]);
    *(float4*)(Xi + off) = make_float4(acci[j][0], acci[j][1], acci[j][2], acci[j][3]);
  }
}

// ---------------- stage B: per-(h,m) complex mode mixing ----------------
// O[b][h][m][o] = sum_i X[b][h][m][i] * W[h][m][i][o]   (complex)
__global__ __launch_bounds__(256) void mix_k(const float* __restrict__ Xr, const float* __restrict__ Xi,
                                             const float* __restrict__ Wtr, const float* __restrict__ Wti,
                                             float* __restrict__ Or_, float* __restrict__ Oi_) {
  int bid = blockIdx.x;               // h*NM + m
  int h = bid >> 6, m = bid & 63;
  __shared__ float Xrs[NB][NE];
  __shared__ float Xis[NB][NE];
  int t = threadIdx.x;
  const size_t XPART = (size_t)NB * NH * NM * NE;
  for (int rep = 0; rep < 8; ++rep) {
    int id = rep * 256 + t;           // over NB*NE = 2048
    int bb = id >> 6, ii = id & 63;
    size_t off = (((size_t)bb * NH + h) * NM + m) * NE + ii;
    float sr = 0.f, si = 0.f;
#pragma unroll
    for (int sp = 0; sp < LSPLIT; ++sp) {
      sr += Xr[(size_t)sp * XPART + off];
      si += Xi[(size_t)sp * XPART + off];
    }
    Xrs[bb][ii] = sr;
    Xis[bb][ii] = si;
  }
  __syncthreads();
  int ob = t & 15, bb2 = t >> 4;
  int o0 = ob * 4, b0 = bb2 * 2;
  float ar[2][4] = {{0.f}};
  float ai[2][4] = {{0.f}};
  const float* wrb = Wtr + ((size_t)h * NM + m) * NE * NE;
  const float* wib = Wti + ((size_t)h * NM + m) * NE * NE;
#pragma unroll 2
  for (int i = 0; i < NE; ++i) {
    float4 wr = *(const float4*)(wrb + i * NE + o0);
    float4 wi = *(const float4*)(wib + i * NE + o0);
    float wra[4] = {wr.x, wr.y, wr.z, wr.w};
    float wia[4] = {wi.x, wi.y, wi.z, wi.w};
#pragma unroll
    for (int bj = 0; bj < 2; ++bj) {
      float xr = Xrs[b0 + bj][i];
      float xi = Xis[b0 + bj][i];
#pragma unroll
      for (int k = 0; k < 4; ++k) {
        ar[bj][k] += xr * wra[k] - xi * wia[k];
        ai[bj][k] += xr * wia[k] + xi * wra[k];
      }
    }
  }
#pragma unroll
  for (int bj = 0; bj < 2; ++bj) {
    size_t off = (((size_t)(b0 + bj) * NH + h) * NM + m) * NE + o0;
    *(float4*)(Or_ + off) = make_float4(ar[bj][0], ar[bj][1], ar[bj][2], ar[bj][3]);
    *(float4*)(Oi_ + off) = make_float4(ai[bj][0], ai[bj][1], ai[bj][2], ai[bj][3]);
  }
}

// ---------------- stage C: iDFT over 64 slots ----------------
// out[b][h][o][l'] = sum_m Or[b][h][m][o]*ccT[m][l'] + Oi[b][h][m][o]*csT[m][l']
__global__ __launch_bounds__(256) void idft_k(const float* __restrict__ Or_, const float* __restrict__ Oi_,
                                              const float* __restrict__ ccT, const float* __restrict__ csT,
                                              float* __restrict__ out) {
  int bid = blockIdx.x;               // (b*NH + h)*4 + qt
  int qt = bid & 3;
  int bh = bid >> 2;
  int t = threadIdx.x;
  __shared__ __align__(16) float Ors[NM][NE];
  __shared__ __align__(16) float Ois[NM][NE];
  const float* orb = Or_ + (size_t)bh * NM * NE;
  const float* oib = Oi_ + (size_t)bh * NM * NE;
  for (int rep = 0; rep < 4; ++rep) {  // 4096 floats / (256 thr * 4) = 4 reps
    int id = rep * 256 + t;
    ((float4*)Ors)[id] = ((const float4*)orb)[id];
    ((float4*)Ois)[id] = ((const float4*)oib)[id];
  }
  __syncthreads();
  int lb = t & 63, og = t >> 6;
  int o0 = og * 16;
  float* outb = out + (size_t)bh * NE * NL;
  for (int ch = 0; ch < 8; ++ch) {
    int lp = qt * 512 + ch * 64 + lb;
    float acc[16] = {0.f};
    for (int m = 0; m < NM; ++m) {
      float c = ccT[m * NL + lp];
      float sv = csT[m * NL + lp];
#pragma unroll
      for (int kq = 0; kq < 4; ++kq) {
        float4 orv = *(const float4*)(&Ors[m][o0 + kq * 4]);
        float4 oiv = *(const float4*)(&Ois[m][o0 + kq * 4]);
        acc[kq * 4 + 0] += orv.x * c + oiv.x * sv;
        acc[kq * 4 + 1] += orv.y * c + oiv.y * sv;
        acc[kq * 4 + 2] += orv.z * c + oiv.z * sv;
        acc[kq * 4 + 3] += orv.w * c + oiv.w * sv;
      }
    }
#pragma unroll
    for (int k = 0; k < 16; ++k) {
      outb[(size_t)(o0 + k) * NL + lp] = acc[k];
    }
  }
}

extern "C" void kernel_launch(void* const* d_in, const int* in_sizes, int n_in,
                              void* d_out, int out_size, void* d_ws, size_t ws_size,
                              hipStream_t stream) {
  const float* q = (const float*)d_in[0];
  // d_in[1]=k, d_in[2]=v unused by FourierBlock
  const float* wr = (const float*)d_in[3];
  const float* wi = (const float*)d_in[4];
  const int* index = (const int*)d_in[5];
  float* out = (float*)d_out;
  float* ws = (float*)d_ws;

  constexpr size_t TBL = (size_t)NL * NM;                      // 131072
  constexpr size_t XSZ = (size_t)LSPLIT * NB * NH * NM * NE;   // 4194304
  constexpr size_t OSZ = (size_t)NB * NH * NM * NE;            // 1048576
  constexpr size_t WSZ = (size_t)NH * NM * NE * NE;            // 2097152
  constexpr size_t NEED = 4 * TBL + 2 * XSZ + 2 * OSZ + 2 * WSZ;
  if (ws_size < NEED * sizeof(float)) return;  // fail loudly via absmax rather than corrupt

  float* cosTt = ws;
  float* sinTt = cosTt + TBL;
  float* ccT = sinTt + TBL;
  float* csT = ccT + TBL;
  float* Xr = csT + TBL;
  float* Xi = Xr + XSZ;
  float* Or_ = Xi + XSZ;
  float* Oi_ = Or_ + OSZ;
  float* Wtr = Oi_ + OSZ;
  float* Wti = Wtr + WSZ;

  hipLaunchKernelGGL(build_tables_k, dim3(512), dim3(256), 0, stream, index, cosTt, sinTt, ccT, csT);
  hipLaunchKernelGGL(transpose_w_k, dim3(512), dim3(256), 0, stream, wr, wi, Wtr, Wti);
  hipLaunchKernelGGL(dft_k, dim3(NB * NH * LSPLIT), dim3(256), 0, stream, q, cosTt, sinTt, Xr, Xi);
  hipLaunchKernelGGL(mix_k, dim3(NH * NM), dim3(256), 0, stream, Xr, Xi, Wtr, Wti, Or_, Oi_);
  hipLaunchKernelGGL(idft_k, dim3(NB * NH * 4), dim3(256), 0, stream, Or_, Oi_, ccT, csT, out);
}

// Round 2
// 113.525 us; speedup vs baseline: 5.6110x; 5.6110x over previous
//
#include <hip/hip_runtime.h>
#include <math.h>

#define NB 32
#define NL 2048
#define NH 8
#define NE 64
#define NM 64
#define MRI 128          // 2*NM rows (re stacked over im)
#define KS 2             // K-split for dft grid
#define BKA 64           // K-chunk for dft

typedef __attribute__((ext_vector_type(8))) __bf16 bf16x8;
typedef __attribute__((ext_vector_type(8))) unsigned short us8;
typedef __attribute__((ext_vector_type(4))) float f32x4;
typedef __attribute__((ext_vector_type(16))) float f32x16;

// fp32 -> bf16 RNE
__device__ __forceinline__ unsigned short f2bf(float x) {
  unsigned int u = __builtin_bit_cast(unsigned int, x);
  u = (u + 0x7fffu + ((u >> 16) & 1u)) >> 16;
  return (unsigned short)u;
}

__device__ __forceinline__ void gll16(const void* g, void* l) {
  __builtin_amdgcn_global_load_lds(
      (const __attribute__((address_space(1))) void*)g,
      (__attribute__((address_space(3))) void*)l, 16, 0, 0);
}

// ---------------- tables ----------------
// T  [128][2048] bf16 : row m   = cos(2*pi*f_m*l/L); row 64+m = -sin(...)
// IT [2048][128] bf16 : col m   = scale_m*cos(2*pi*m*l'/L); col 64+m = -scale_m*sin(...)
__global__ void tables_k(const int* __restrict__ idx, unsigned short* __restrict__ T,
                         unsigned short* __restrict__ IT) {
  int gid = blockIdx.x * blockDim.x + threadIdx.x;  // 0..262143
  const float w0 = 6.283185307179586f / (float)NL;
  {
    int row = gid >> 11, l = gid & (NL - 1);
    int m = row & 63;
    int f = idx[m];
    float th = (float)((f * l) & (NL - 1)) * w0;
    float s, c;
    sincosf(th, &s, &c);
    T[gid] = f2bf(row < 64 ? c : -s);
  }
  {
    int lp = gid >> 7, k = gid & 127;
    int m = k & 63;
    float th = (float)((m * lp) & (NL - 1)) * w0;
    float s, c;
    sincosf(th, &s, &c);
    float v;
    if (k < 64) v = ((m == 0 ? 1.0f : 2.0f) / (float)NL) * c;
    else        v = (m == 0 ? 0.0f : (-2.0f / (float)NL) * s);
    IT[gid] = f2bf(v);
  }
}

// ---------------- stage A: X = T * q  (bf16 MFMA, fp32 acc) ----------------
// grid: (b*NH+h)*KS + s ; block 256 = 4 waves; C tile [128 m_ri][64 e], K = 1024
__global__ __launch_bounds__(256) void dft_k(const float* __restrict__ q,
                                             const unsigned short* __restrict__ T,
                                             float* __restrict__ X2) {
  int bid = blockIdx.x;
  int s = bid & 1, h = (bid >> 1) & 7, b = bid >> 4;
  int t = threadIdx.x, lane = t & 63, wid = t >> 6;
  __shared__ unsigned short Al[2][MRI * BKA];  // [row 128][k 64] rows 128B, XOR-swizzled
  __shared__ unsigned short Bl[2][NE * BKA];   // [e 64][l 64]  rows 128B, XOR-swizzled
  const float* qb = q + (size_t)b * NL * NH * NE + h * NE;  // q[b][l][h][e]
  int k0b = s * (NL / KS);
  f32x4 acc[4][2] = {};

  auto stageA = [&](int bufi, int k0) {
#pragma unroll
    for (int n = 0; n < 4; ++n) {
      int lin = n * 4096 + wid * 1024 + lane * 16;
      int row = lin >> 7;
      int colb = (lin & 127) ^ ((row & 7) << 4);   // pre-swizzled global source
      gll16((const char*)T + (size_t)row * (NL * 2) + (size_t)k0 * 2 + colb,
            (char*)&Al[bufi][0] + n * 4096 + wid * 1024);
    }
  };
  auto stageBload = [&](f32x4* stg, int k0) {
#pragma unroll
    for (int r = 0; r < 4; ++r) {
      int id = r * 256 + t;
      int lr = id >> 4;           // l within chunk
      int e0 = (id & 15) * 4;
      stg[r] = *(const f32x4*)(qb + (size_t)(k0 + lr) * (NH * NE) + e0);
    }
  };
  auto stageBwrite = [&](int bufi, const f32x4* stg) {
#pragma unroll
    for (int r = 0; r < 4; ++r) {
      int id = r * 256 + t;
      int lr = id >> 4;
      int e0 = (id & 15) * 4;
#pragma unroll
      for (int j = 0; j < 4; ++j) {
        int e = e0 + j;
        int off = ((e << 7) + (lr << 1)) ^ ((e & 7) << 4);
        *(unsigned short*)((char*)&Bl[bufi][0] + off) = f2bf(stg[r][j]);
      }
    }
  };
  auto compute = [&](int bufi) {
#pragma unroll
    for (int ks2 = 0; ks2 < 2; ++ks2) {
      bf16x8 bfr[2];
#pragma unroll
      for (int fn = 0; fn < 2; ++fn) {
        int e = ((wid & 1) << 5) + (fn << 4) + (lane & 15);
        int off = ((e << 7) + (ks2 << 6) + ((lane >> 4) << 4)) ^ ((e & 7) << 4);
        bfr[fn] = __builtin_bit_cast(bf16x8, *(const us8*)((const char*)&Bl[bufi][0] + off));
      }
#pragma unroll
      for (int fm = 0; fm < 4; ++fm) {
        int row = ((wid >> 1) << 6) + (fm << 4) + (lane & 15);
        int off = ((row << 7) + (ks2 << 6) + ((lane >> 4) << 4)) ^ ((row & 7) << 4);
        bf16x8 afr = __builtin_bit_cast(bf16x8, *(const us8*)((const char*)&Al[bufi][0] + off));
#pragma unroll
        for (int fn = 0; fn < 2; ++fn)
          acc[fm][fn] = __builtin_amdgcn_mfma_f32_16x16x32_bf16(afr, bfr[fn], acc[fm][fn], 0, 0, 0);
      }
    }
  };

  {
    f32x4 stg[4];
    stageA(0, k0b);
    stageBload(stg, k0b);
    stageBwrite(0, stg);
  }
  __syncthreads();
  const int NCH = (NL / KS) / BKA;  // 16
  for (int c = 0; c < NCH; ++c) {
    int cur = c & 1;
    f32x4 stg[4];
    bool more = (c + 1) < NCH;
    if (more) {
      stageA(cur ^ 1, k0b + (c + 1) * BKA);
      stageBload(stg, k0b + (c + 1) * BKA);
    }
    compute(cur);
    if (more) stageBwrite(cur ^ 1, stg);
    __syncthreads();
  }
  // X2[bid][128][64] fp32 ; C frag (16x16): col=lane&15, row=(lane>>4)*4+reg
  float* Xo = X2 + (size_t)bid * (MRI * NE);
#pragma unroll
  for (int fm = 0; fm < 4; ++fm)
#pragma unroll
    for (int fn = 0; fn < 2; ++fn)
#pragma unroll
      for (int r4 = 0; r4 < 4; ++r4) {
        int row = ((wid >> 1) << 6) + (fm << 4) + ((lane >> 4) << 2) + r4;
        int col = ((wid & 1) << 5) + (fn << 4) + (lane & 15);
        Xo[row * NE + col] = acc[fm][fn][r4];
      }
}

// ---------------- stage B: per-(h,m) complex mix, fp32 ----------------
// O[b][h][o][m_ri] bf16
__global__ __launch_bounds__(256) void mix_k(const float* __restrict__ X2,
                                             const float* __restrict__ wr,
                                             const float* __restrict__ wi,
                                             unsigned short* __restrict__ O) {
  int h = blockIdx.x >> 6, m = blockIdx.x & 63;
  __shared__ float Wrs[64 * 64];
  __shared__ float Wis[64 * 64];
  __shared__ float Xrs[32][65];
  __shared__ float Xis[32][65];
  int t = threadIdx.x;
  const float* wrb = wr + (size_t)h * (64 * 64 * 64) + m;  // [i][o][m]
  const float* wib = wi + (size_t)h * (64 * 64 * 64) + m;
  for (int rep = 0; rep < 16; ++rep) {
    int id = rep * 256 + t;  // i*64 + o
    Wrs[id] = wrb[(size_t)id * 64];
    Wis[id] = wib[(size_t)id * 64];
  }
  for (int rep = 0; rep < 8; ++rep) {
    int id = rep * 256 + t;  // b*64 + e
    int bb = id >> 6, e = id & 63;
    size_t base = (size_t)(bb * NH + h) * KS * (MRI * NE);
    Xrs[bb][e] = X2[base + (size_t)m * NE + e] + X2[base + MRI * NE + (size_t)m * NE + e];
    Xis[bb][e] = X2[base + (size_t)(64 + m) * NE + e] + X2[base + MRI * NE + (size_t)(64 + m) * NE + e];
  }
  __syncthreads();
  int o0 = (t & 15) * 4, b0 = (t >> 4) * 2;
  float ar[2][4] = {{0.f}}, ai[2][4] = {{0.f}};
  for (int i = 0; i < 64; ++i) {
    f32x4 wrv = *(const f32x4*)&Wrs[i * 64 + o0];
    f32x4 wiv = *(const f32x4*)&Wis[i * 64 + o0];
#pragma unroll
    for (int bj = 0; bj < 2; ++bj) {
      float xr = Xrs[b0 + bj][i], xi = Xis[b0 + bj][i];
#pragma unroll
      for (int k = 0; k < 4; ++k) {
        ar[bj][k] += xr * wrv[k] - xi * wiv[k];
        ai[bj][k] += xr * wiv[k] + xi * wrv[k];
      }
    }
  }
#pragma unroll
  for (int bj = 0; bj < 2; ++bj)
#pragma unroll
    for (int k = 0; k < 4; ++k) {
      size_t ob = (((size_t)(b0 + bj) * NH + h) * NE + (o0 + k)) * MRI;
      O[ob + m] = f2bf(ar[bj][k]);
      O[ob + 64 + m] = f2bf(ai[bj][k]);
    }
}

// ---------------- stage C: out = O * ITt (bf16 MFMA, fp32 acc) ----------------
// grid: b(32) x rowtile(4) x coltile(16); block tile [128 (h,o)][128 l'], K=128
__global__ __launch_bounds__(256) void idft_k(const unsigned short* __restrict__ O,
                                              const unsigned short* __restrict__ IT,
                                              float* __restrict__ out) {
  int bid = blockIdx.x;
  int ct = bid & 15, rt = (bid >> 4) & 3, b = bid >> 6;
  int t = threadIdx.x, lane = t & 63, wid = t >> 6;
  __shared__ unsigned short Als[128 * 128];  // O rows 256B, swizzled
  __shared__ unsigned short Bls[128 * 128];  // ITt rows 256B, swizzled
  const unsigned short* Og = O + ((size_t)b * 512 + rt * 128) * MRI;
  const unsigned short* Ig = IT + (size_t)ct * 128 * MRI;
#pragma unroll
  for (int n = 0; n < 8; ++n) {
    int lin = n * 4096 + wid * 1024 + lane * 16;
    int row = lin >> 8;
    int colb = (lin & 255) ^ ((row & 7) << 4);
    gll16((const char*)Og + (size_t)row * 256 + colb, (char*)Als + n * 4096 + wid * 1024);
  }
#pragma unroll
  for (int n = 0; n < 8; ++n) {
    int lin = n * 4096 + wid * 1024 + lane * 16;
    int row = lin >> 8;
    int colb = (lin & 255) ^ ((row & 7) << 4);
    gll16((const char*)Ig + (size_t)row * 256 + colb, (char*)Bls + n * 4096 + wid * 1024);
  }
  __syncthreads();
  int wr2 = (wid >> 1) * 64, wc = (wid & 1) * 64;
  f32x16 acc[2][2] = {};
#pragma unroll
  for (int ksp = 0; ksp < 8; ++ksp) {
    bf16x8 af[2], bfv[2];
#pragma unroll
    for (int i2 = 0; i2 < 2; ++i2) {
      int row = wr2 + i2 * 32 + (lane & 31);
      int off = ((row << 8) + (ksp << 5) + ((lane >> 5) << 4)) ^ ((row & 7) << 4);
      af[i2] = __builtin_bit_cast(bf16x8, *(const us8*)((const char*)Als + off));
      int nr = wc + i2 * 32 + (lane & 31);
      int off2 = ((nr << 8) + (ksp << 5) + ((lane >> 5) << 4)) ^ ((nr & 7) << 4);
      bfv[i2] = __builtin_bit_cast(bf16x8, *(const us8*)((const char*)Bls + off2));
    }
#pragma unroll
    for (int i2 = 0; i2 < 2; ++i2)
#pragma unroll
      for (int j2 = 0; j2 < 2; ++j2)
        acc[i2][j2] = __builtin_amdgcn_mfma_f32_32x32x16_bf16(af[i2], bfv[j2], acc[i2][j2], 0, 0, 0);
  }
  // C frag (32x32): col=lane&31, row=(reg&3)+8*(reg>>2)+4*(lane>>5)
  float* ob = out + ((size_t)b * 512 + rt * 128) * NL + ct * 128;
#pragma unroll
  for (int i2 = 0; i2 < 2; ++i2)
#pragma unroll
    for (int j2 = 0; j2 < 2; ++j2)
#pragma unroll
      for (int rg = 0; rg < 16; ++rg) {
        int row = wr2 + i2 * 32 + ((rg & 3) + 8 * (rg >> 2) + 4 * (lane >> 5));
        int col = wc + j2 * 32 + (lane & 31);
        ob[(size_t)row * NL + col] = acc[i2][j2][rg];
      }
}

extern "C" void kernel_launch(void* const* d_in, const int* in_sizes, int n_in,
                              void* d_out, int out_size, void* d_ws, size_t ws_size,
                              hipStream_t stream) {
  const float* q = (const float*)d_in[0];
  const float* wr = (const float*)d_in[3];
  const float* wi = (const float*)d_in[4];
  const int* idx = (const int*)d_in[5];
  float* out = (float*)d_out;
  char* ws = (char*)d_ws;

  constexpr size_t TBYTES = (size_t)MRI * NL * 2;                    // 512KB
  constexpr size_t X2ELEM = (size_t)NB * NH * KS * MRI * NE;         // 4,194,304 f32
  constexpr size_t OELEM = (size_t)NB * NH * NE * MRI;               // 2,097,152 bf16
  constexpr size_t NEED = 2 * TBYTES + X2ELEM * 4 + OELEM * 2;
  if (ws_size < NEED) return;

  unsigned short* T = (unsigned short*)ws;
  unsigned short* IT = (unsigned short*)(ws + TBYTES);
  float* X2 = (float*)(ws + 2 * TBYTES);
  unsigned short* O = (unsigned short*)(ws + 2 * TBYTES + X2ELEM * 4);

  hipLaunchKernelGGL(tables_k, dim3(1024), dim3(256), 0, stream, idx, T, IT);
  hipLaunchKernelGGL(dft_k, dim3(NB * NH * KS), dim3(256), 0, stream, q, T, X2);
  hipLaunchKernelGGL(mix_k, dim3(NH * NM), dim3(256), 0, stream, X2, wr, wi, O);
  hipLaunchKernelGGL(idft_k, dim3(NB * 4 * 16), dim3(256), 0, stream, O, IT, out);
}